// Round 7
// baseline (126.661 us; speedup 1.0000x reference)
//
#include <hip/hip_runtime.h>

#define WN 4096   // nodes per level
#define BN 256    // batch
#define KN 8      // parents per node
#define NLVL 15   // levels after the prior
#define NTHR 1024 // 16 waves
#define NPT (WN / NTHR)

// ---- prep2: bank-balanced slot permutation + param packing ----
// One wave (64 threads) per 64-node gather group. For slot k (one ds_read_b32
// wave-instr in the main kernel), greedily pick each node's parent so the 64
// lanes' banks (p%32) stay <=2 per bank (free per m136). Weights/parents are
// permuted together per-lane, so correctness never depends on the histogram.
__global__ __launch_bounds__(64) void prep2_kernel(
    const float* __restrict__ wts, const float* __restrict__ bia,
    const int* __restrict__ par,   const int* __restrict__ inv,
    float4* __restrict__ Wp, uint4* __restrict__ Pp, float* __restrict__ Bz) {
  __shared__ unsigned cnt[32];
  const int lane = threadIdx.x;
  const int idx  = blockIdx.x * 64 + lane;   // flat over NLVL*WN
  const int4   pA = *(const int4*)(par + (size_t)idx * KN);
  const int4   pB = *(const int4*)(par + (size_t)idx * KN + 4);
  const float4 wA = *(const float4*)(wts + (size_t)idx * KN);
  const float4 wB = *(const float4*)(wts + (size_t)idx * KN + 4);
  const bool   iv = inv[idx] != 0;
  const float  sw = ((wA.x + wA.y) + (wA.z + wA.w)) + ((wB.x + wB.y) + (wB.z + wB.w));
  const float  s  = iv ? -1.0f : 1.0f;
  const int   p0 = pA.x, p1 = pA.y, p2 = pA.z, p3 = pA.w;
  const int   p4 = pB.x, p5 = pB.y, p6 = pB.z, p7 = pB.w;
  const float w0 = wA.x * s, w1 = wA.y * s, w2 = wA.z * s, w3 = wA.w * s;
  const float w4 = wB.x * s, w5 = wB.y * s, w6 = wB.z * s, w7 = wB.w * s;

  unsigned mask = 0xffu;       // unassigned parents
  unsigned slotpack = 0;       // 4 bits per parent j: its slot

  for (int k = 0; k < KN; ++k) {
    if (lane < 32) cnt[lane] = 0;
    __syncthreads();
    bool done = false;
    for (int it = 0; it < 3; ++it) {
      if (!done) {
        // argmin over remaining parents of cnt[bank] — all indices compile-time
        unsigned bestj = 8, bestv = 0xffffffffu;
#define SCAN(J, PJ) if (mask & (1u << (J))) { unsigned v = cnt[(PJ) & 31]; if (v < bestv) { bestv = v; bestj = (J); } }
        SCAN(0, p0) SCAN(1, p1) SCAN(2, p2) SCAN(3, p3)
        SCAN(4, p4) SCAN(5, p5) SCAN(6, p6) SCAN(7, p7)
#undef SCAN
        const unsigned bank =
            (bestj == 0) ? (p0 & 31) : (bestj == 1) ? (p1 & 31) :
            (bestj == 2) ? (p2 & 31) : (bestj == 3) ? (p3 & 31) :
            (bestj == 4) ? (p4 & 31) : (bestj == 5) ? (p5 & 31) :
            (bestj == 6) ? (p6 & 31) : (p7 & 31);
        const unsigned cap = (it < 2) ? 2u : 3u;
        const unsigned old = atomicAdd(&cnt[bank], 1u);
        if (old < cap) {
          slotpack |= (unsigned)k << (4u * bestj);
          mask &= ~(1u << bestj);
          done = true;
        } else {
          atomicAdd(&cnt[bank], (unsigned)-1);
        }
      }
      __syncthreads();
    }
    if (!done) {   // force-assign lowest remaining parent
      const unsigned bestj = (unsigned)__ffs(mask) - 1u;
      slotpack |= (unsigned)k << (4u * bestj);
      mask &= ~(1u << bestj);
    }
    __syncthreads();
  }

  // emit permuted (parent, weight) pairs — all selects compile-time indexed
#define SLOT_OF(J) ((slotpack >> (4u * (J))) & 15u)
#define PICKW(K) (SLOT_OF(0) == (K) ? w0 : SLOT_OF(1) == (K) ? w1 : \
                  SLOT_OF(2) == (K) ? w2 : SLOT_OF(3) == (K) ? w3 : \
                  SLOT_OF(4) == (K) ? w4 : SLOT_OF(5) == (K) ? w5 : \
                  SLOT_OF(6) == (K) ? w6 : w7)
#define PICKP(K) (unsigned)(SLOT_OF(0) == (K) ? p0 : SLOT_OF(1) == (K) ? p1 : \
                  SLOT_OF(2) == (K) ? p2 : SLOT_OF(3) == (K) ? p3 : \
                  SLOT_OF(4) == (K) ? p4 : SLOT_OF(5) == (K) ? p5 : \
                  SLOT_OF(6) == (K) ? p6 : p7)
  const float ow0 = PICKW(0), ow1 = PICKW(1), ow2 = PICKW(2), ow3 = PICKW(3);
  const float ow4 = PICKW(4), ow5 = PICKW(5), ow6 = PICKW(6), ow7 = PICKW(7);
  const unsigned op0 = PICKP(0), op1 = PICKP(1), op2 = PICKP(2), op3 = PICKP(3);
  const unsigned op4 = PICKP(4), op5 = PICKP(5), op6 = PICKP(6), op7 = PICKP(7);
#undef SLOT_OF
#undef PICKW
#undef PICKP
  Pp[idx] = make_uint4(op0 | (op1 << 16), op2 | (op3 << 16),
                       op4 | (op5 << 16), op6 | (op7 << 16));
  Wp[(size_t)idx * 2]     = make_float4(ow0, ow1, ow2, ow3);
  Wp[(size_t)idx * 2 + 1] = make_float4(ow4, ow5, ow6, ow7);
  Bz[idx] = iv ? bia[idx] + sw : bia[idx];
}

// ---- main: one block per batch column; 15-level chain in 32KB LDS (unchanged) ----
__global__ __launch_bounds__(NTHR) void fused_lds_kernel(
    const float* __restrict__ obs, const float* __restrict__ pw,
    const float* __restrict__ pb,  const float4* __restrict__ Wp,
    const uint4* __restrict__ Pp,  const float* __restrict__ Bz,
    float* __restrict__ out) {
  __shared__ float h[2][WN];
  const int    t = threadIdx.x;
  const size_t b = blockIdx.x;

  uint4 pp[2][NPT];
  float bz[2][NPT];

#pragma unroll
  for (int i = 0; i < NPT; ++i) {
    pp[0][i] = Pp[i * NTHR + t];
    bz[0][i] = Bz[i * NTHR + t];
  }
#pragma unroll
  for (int i = 0; i < NPT; ++i) {
    const int n = i * NTHR + t;
    h[0][n] = fmaxf(fmaf(obs[b * WN + n], pw[n], pb[n]), 0.0f);
  }
  __syncthreads();

#pragma unroll
  for (int l = 0; l < NLVL; ++l) {
    const int cb = l & 1;
    const int nb = cb ^ 1;
    const float* hc = h[l & 1];
    float*       hn = h[(l + 1) & 1];

    if (l + 1 < NLVL) {
#pragma unroll
      for (int i = 0; i < NPT; ++i) {
        const size_t nl = (size_t)(l + 1) * WN + i * NTHR + t;
        pp[nb][i] = Pp[nl];
        bz[nb][i] = Bz[nl];
      }
    }

    float4 w0[NPT], w1[NPT];
#pragma unroll
    for (int i = 0; i < NPT; ++i) {
      const size_t nl = (size_t)l * WN + i * NTHR + t;
      w0[i] = Wp[nl * 2];
      w1[i] = Wp[nl * 2 + 1];
    }

#pragma unroll
    for (int i = 0; i < NPT; ++i) {
      const uint4 p = pp[cb][i];
      const float x0 = hc[p.x & 0xffffu];
      const float x1 = hc[p.x >> 16];
      const float x2 = hc[p.y & 0xffffu];
      const float x3 = hc[p.y >> 16];
      const float x4 = hc[p.z & 0xffffu];
      const float x5 = hc[p.z >> 16];
      const float x6 = hc[p.w & 0xffffu];
      const float x7 = hc[p.w >> 16];
      float acc = bz[cb][i];
      acc = fmaf(x0, w0[i].x, acc);
      acc = fmaf(x1, w0[i].y, acc);
      acc = fmaf(x2, w0[i].z, acc);
      acc = fmaf(x3, w0[i].w, acc);
      acc = fmaf(x4, w1[i].x, acc);
      acc = fmaf(x5, w1[i].y, acc);
      acc = fmaf(x6, w1[i].z, acc);
      acc = fmaf(x7, w1[i].w, acc);
      hn[i * NTHR + t] = fmaxf(acc, 0.0f);
    }
    __syncthreads();
  }

#pragma unroll
  for (int i = 0; i < NPT; ++i) {
    const int n = i * NTHR + t;
    out[b * WN + n] = h[NLVL & 1][n];
  }
}

extern "C" void kernel_launch(void* const* d_in, const int* in_sizes, int n_in,
                              void* d_out, int out_size, void* d_ws, size_t ws_size,
                              hipStream_t stream) {
  const float* obs = (const float*)d_in[0];
  const float* pw  = (const float*)d_in[1];
  const float* pb  = (const float*)d_in[2];
  const float* wts = (const float*)d_in[3];
  const float* bia = (const float*)d_in[4];
  const int*   par = (const int*)d_in[5];
  const int*   inv = (const int*)d_in[6];
  float* out = (float*)d_out;

  // d_ws layout (≈3.2 MB): Wp | Pp | Bz
  char* ws = (char*)d_ws;
  float4* Wp = (float4*)ws;                                     // 15*4096*32 B
  uint4*  Pp = (uint4*)(ws + (size_t)NLVL * WN * 32);           // 15*4096*16 B
  float*  Bz = (float*)(ws + (size_t)NLVL * WN * 48);           // 15*4096*4 B

  prep2_kernel<<<(NLVL * WN) / 64, 64, 0, stream>>>(wts, bia, par, inv, Wp, Pp, Bz);
  fused_lds_kernel<<<BN, NTHR, 0, stream>>>(obs, pw, pb, Wp, Pp, Bz, out);
}

// Round 10
// 106.012 us; speedup vs baseline: 1.1948x; 1.1948x over previous
//
#include <hip/hip_runtime.h>
#include <hip/hip_fp16.h>

#define WN 4096   // nodes per level
#define BN 256    // batch
#define KN 8      // parents per node
#define NLVL 15   // levels after the prior
#define NTHR 1024 // 16 waves
#define NPT (WN / NTHR)

// ---- prep: one-pass bank-balanced slot permutation + fp16 param packing ----
// 256 threads = 4 waves; per-wave private 32-bin histogram. For each of the 8
// gather slots: every lane picks its remaining parent with min bank count and
// atomically claims it (no retry — approximate balance, exact correctness:
// parent and weight are permuted together per-lane).
// Wh: uint4[NLVL*WN]  8 x fp16 signed weights (inv folded in)
// Pp: uint4[NLVL*WN]  8 x u16 parents (slot-permuted with weights)
// Bz: float[NLVL*WN]  base = bias + iv*sum(w)
__global__ __launch_bounds__(256) void prep_kernel(
    const float* __restrict__ wts, const float* __restrict__ bia,
    const int* __restrict__ par,   const int* __restrict__ inv,
    uint4* __restrict__ Wh, uint4* __restrict__ Pp, float* __restrict__ Bz) {
  __shared__ unsigned cnt[4][32];
  const int t    = threadIdx.x;
  const int wv   = t >> 6;
  const int lane = t & 63;
  const int idx  = blockIdx.x * 256 + t;     // flat over NLVL*WN
  unsigned* c = cnt[wv];

  const int4   pA = *(const int4*)(par + (size_t)idx * KN);
  const int4   pB = *(const int4*)(par + (size_t)idx * KN + 4);
  const float4 wA = *(const float4*)(wts + (size_t)idx * KN);
  const float4 wB = *(const float4*)(wts + (size_t)idx * KN + 4);
  const bool   iv = inv[idx] != 0;
  const float  sw = ((wA.x + wA.y) + (wA.z + wA.w)) + ((wB.x + wB.y) + (wB.z + wB.w));
  const float  s  = iv ? -1.0f : 1.0f;
  const int   p0 = pA.x, p1 = pA.y, p2 = pA.z, p3 = pA.w;
  const int   p4 = pB.x, p5 = pB.y, p6 = pB.z, p7 = pB.w;
  const float w0 = wA.x * s, w1 = wA.y * s, w2 = wA.z * s, w3 = wA.w * s;
  const float w4 = wB.x * s, w5 = wB.y * s, w6 = wB.z * s, w7 = wB.w * s;

  unsigned mask = 0xffu;
  unsigned op[KN];
  float    ow[KN];

#pragma unroll
  for (int k = 0; k < KN; ++k) {
    __syncthreads();
    if (lane < 32) c[lane] = 0;
    __syncthreads();
    unsigned bestj = 0, bestv = 0xffffffffu;
#define SCAN(J, PJ) if (mask & (1u << (J))) { unsigned v = c[(PJ) & 31]; if (v < bestv) { bestv = v; bestj = (J); } }
    SCAN(0, p0) SCAN(1, p1) SCAN(2, p2) SCAN(3, p3)
    SCAN(4, p4) SCAN(5, p5) SCAN(6, p6) SCAN(7, p7)
#undef SCAN
    const unsigned pj =
        (bestj == 0) ? (unsigned)p0 : (bestj == 1) ? (unsigned)p1 :
        (bestj == 2) ? (unsigned)p2 : (bestj == 3) ? (unsigned)p3 :
        (bestj == 4) ? (unsigned)p4 : (bestj == 5) ? (unsigned)p5 :
        (bestj == 6) ? (unsigned)p6 : (unsigned)p7;
    const float wj =
        (bestj == 0) ? w0 : (bestj == 1) ? w1 :
        (bestj == 2) ? w2 : (bestj == 3) ? w3 :
        (bestj == 4) ? w4 : (bestj == 5) ? w5 :
        (bestj == 6) ? w6 : w7;
    atomicAdd(&c[pj & 31], 1u);
    op[k] = pj;
    ow[k] = wj;
    mask &= ~(1u << bestj);
  }

  Pp[idx] = make_uint4(op[0] | (op[1] << 16), op[2] | (op[3] << 16),
                       op[4] | (op[5] << 16), op[6] | (op[7] << 16));
  uint4 wq;
  wq.x = (unsigned)__half_as_ushort(__float2half(ow[0])) |
         ((unsigned)__half_as_ushort(__float2half(ow[1])) << 16);
  wq.y = (unsigned)__half_as_ushort(__float2half(ow[2])) |
         ((unsigned)__half_as_ushort(__float2half(ow[3])) << 16);
  wq.z = (unsigned)__half_as_ushort(__float2half(ow[4])) |
         ((unsigned)__half_as_ushort(__float2half(ow[5])) << 16);
  wq.w = (unsigned)__half_as_ushort(__float2half(ow[6])) |
         ((unsigned)__half_as_ushort(__float2half(ow[7])) << 16);
  Wh[idx] = wq;
  Bz[idx] = iv ? bia[idx] + sw : bia[idx];
}

// ---- main: one block per batch column; 15-level chain in 32KB LDS.
// Parents/base software-pipelined across the level barrier; fp16 weights
// loaded per level before the gathers so L2 traffic overlaps the LDS pipe.
__global__ __launch_bounds__(NTHR) void fused_lds_kernel(
    const float* __restrict__ obs, const float* __restrict__ pw,
    const float* __restrict__ pb,  const uint4* __restrict__ Wh,
    const uint4* __restrict__ Pp,  const float* __restrict__ Bz,
    float* __restrict__ out) {
  __shared__ float h[2][WN];
  const int    t = threadIdx.x;
  const size_t b = blockIdx.x;

  uint4 pp[2][NPT];
  float bz[2][NPT];

#pragma unroll
  for (int i = 0; i < NPT; ++i) {
    pp[0][i] = Pp[i * NTHR + t];
    bz[0][i] = Bz[i * NTHR + t];
  }
#pragma unroll
  for (int i = 0; i < NPT; ++i) {
    const int n = i * NTHR + t;
    h[0][n] = fmaxf(fmaf(obs[b * WN + n], pw[n], pb[n]), 0.0f);
  }
  __syncthreads();

#pragma unroll
  for (int l = 0; l < NLVL; ++l) {
    const int cb = l & 1;
    const int nb = cb ^ 1;
    const float* hc = h[l & 1];
    float*       hn = h[(l + 1) & 1];

    // prefetch NEXT level's parents/base (h-independent)
    if (l + 1 < NLVL) {
#pragma unroll
      for (int i = 0; i < NPT; ++i) {
        const size_t nl = (size_t)(l + 1) * WN + i * NTHR + t;
        pp[nb][i] = Pp[nl];
        bz[nb][i] = Bz[nl];
      }
    }

    // current level's packed fp16 weights — L2 reads overlap the LDS gathers
    uint4 wq[NPT];
#pragma unroll
    for (int i = 0; i < NPT; ++i)
      wq[i] = Wh[(size_t)l * WN + i * NTHR + t];

#pragma unroll
    for (int i = 0; i < NPT; ++i) {
      const uint4 p = pp[cb][i];
      const float x0 = hc[p.x & 0xffffu];
      const float x1 = hc[p.x >> 16];
      const float x2 = hc[p.y & 0xffffu];
      const float x3 = hc[p.y >> 16];
      const float x4 = hc[p.z & 0xffffu];
      const float x5 = hc[p.z >> 16];
      const float x6 = hc[p.w & 0xffffu];
      const float x7 = hc[p.w >> 16];
      const __half2* hw = reinterpret_cast<const __half2*>(&wq[i]);
      const float2 f01 = __half22float2(hw[0]);
      const float2 f23 = __half22float2(hw[1]);
      const float2 f45 = __half22float2(hw[2]);
      const float2 f67 = __half22float2(hw[3]);
      float acc = bz[cb][i];
      acc = fmaf(x0, f01.x, acc);
      acc = fmaf(x1, f01.y, acc);
      acc = fmaf(x2, f23.x, acc);
      acc = fmaf(x3, f23.y, acc);
      acc = fmaf(x4, f45.x, acc);
      acc = fmaf(x5, f45.y, acc);
      acc = fmaf(x6, f67.x, acc);
      acc = fmaf(x7, f67.y, acc);
      hn[i * NTHR + t] = fmaxf(acc, 0.0f);
    }
    __syncthreads();
  }

#pragma unroll
  for (int i = 0; i < NPT; ++i) {
    const int n = i * NTHR + t;
    out[b * WN + n] = h[NLVL & 1][n];
  }
}

extern "C" void kernel_launch(void* const* d_in, const int* in_sizes, int n_in,
                              void* d_out, int out_size, void* d_ws, size_t ws_size,
                              hipStream_t stream) {
  const float* obs = (const float*)d_in[0];
  const float* pw  = (const float*)d_in[1];
  const float* pb  = (const float*)d_in[2];
  const float* wts = (const float*)d_in[3];
  const float* bia = (const float*)d_in[4];
  const int*   par = (const int*)d_in[5];
  const int*   inv = (const int*)d_in[6];
  float* out = (float*)d_out;

  // d_ws layout (≈2.2 MB): Wh | Pp | Bz
  char* ws = (char*)d_ws;
  uint4* Wh = (uint4*)ws;                                       // 15*4096*16 B
  uint4* Pp = (uint4*)(ws + (size_t)NLVL * WN * 16);            // 15*4096*16 B
  float* Bz = (float*)(ws + (size_t)NLVL * WN * 32);            // 15*4096*4 B

  prep_kernel<<<(NLVL * WN) / 256, 256, 0, stream>>>(wts, bia, par, inv, Wh, Pp, Bz);
  fused_lds_kernel<<<BN, NTHR, 0, stream>>>(obs, pw, pb, Wh, Pp, Bz, out);
}